// Round 15
// baseline (232.244 us; speedup 1.0000x reference)
//
#include <hip/hip_runtime.h>
#include <stdint.h>

typedef __bf16 bf16;
typedef __bf16 bf16x8 __attribute__((ext_vector_type(8)));
typedef __bf16 bf16x4 __attribute__((ext_vector_type(4)));
typedef float  f32x4  __attribute__((ext_vector_type(4)));

#define E_DIM 1024
#define S_LEN 2048
#define BATCH 2
#define NH 16
#define DH 64

#define NEG_INF (-__builtin_inff())

__device__ __forceinline__ bf16x8 cvt8(float4 u0, float4 u1) {
    bf16x8 v;
    v[0] = (bf16)u0.x; v[1] = (bf16)u0.y; v[2] = (bf16)u0.z; v[3] = (bf16)u0.w;
    v[4] = (bf16)u1.x; v[5] = (bf16)u1.y; v[6] = (bf16)u1.z; v[7] = (bf16)u1.w;
    return v;
}

// ---------------------------------------------------------------------------
// GEMM with FUSED fp32->bf16 conversion: C = A * W^T + bias.
// QKV modes (0/1/2): A = fp32 x, W = fp32 Wq/Wk/Wv — converted inline during
// VGPR staging (convert at ds_write time so the vmcnt wait lands after the
// barrier). Final mode: A = bf16 attn-out, W = fp32 Wo.
// Single-barrier double buffer (R13); LDS stride 40 (padding legal again
// without global_load_lds) -> conflict-free b128 fragment reads.
// mode 0 scales by 0.125 (folded attention scale).
// ---------------------------------------------------------------------------
__global__ __launch_bounds__(256) void gemm_kernel(
    const float* __restrict__ Af, const bf16* __restrict__ Abf,
    const float* __restrict__ W0, const float* __restrict__ W1, const float* __restrict__ W2,
    const float* __restrict__ bias0, const float* __restrict__ bias1, const float* __restrict__ bias2,
    bf16* __restrict__ outQ, bf16* __restrict__ outK, bf16* __restrict__ outVt,
    float* __restrict__ outF, int final_mode)
{
    __shared__ bf16 As[2][128 * 40];   // 10 KB each, 40 KB total
    __shared__ bf16 Bs[2][128 * 40];

    int mode;
    const float* W; const float* bias;
    if (final_mode) { mode = 3; W = W0; bias = bias0; }
    else {
        mode = blockIdx.z;
        W    = (mode == 0) ? W0 : (mode == 1 ? W1 : W2);
        bias = (mode == 0) ? bias0 : (mode == 1 ? bias1 : bias2);
    }

    const int bm = blockIdx.y * 128, bn = blockIdx.x * 128;
    const int t = threadIdx.x;
    const int lane = t & 63, w = t >> 6;
    const int quad = lane >> 4, l16 = lane & 15;
    const int wm = (w & 1) * 64, wn = (w >> 1) * 64;

    // staging chunks: c in {t, t+256}; chunk -> row = c>>2, col = (c&3)*8
    const int r1 = t >> 2,          o1 = (t & 3) * 8;
    const int r2 = (t + 256) >> 2,  o2 = (t & 3) * 8;   // (t+256)&3 == t&3

    const float* Wg1 = W + (size_t)(bn + r1) * E_DIM + o1;
    const float* Wg2 = W + (size_t)(bn + r2) * E_DIM + o2;
    const float* Ag1f = Af  ? Af  + (size_t)(bm + r1) * E_DIM + o1 : nullptr;
    const float* Ag2f = Af  ? Af  + (size_t)(bm + r2) * E_DIM + o2 : nullptr;
    const bf16*  Ag1b = Abf ? Abf + (size_t)(bm + r1) * E_DIM + o1 : nullptr;
    const bf16*  Ag2b = Abf ? Abf + (size_t)(bm + r2) * E_DIM + o2 : nullptr;

    f32x4 acc[4][4];
#pragma unroll
    for (int i = 0; i < 4; i++)
#pragma unroll
        for (int j = 0; j < 4; j++) acc[i][j] = f32x4{0.f, 0.f, 0.f, 0.f};

    // staged tile registers
    float4 wa0, wa1, wb0, wb1;        // W chunks (always fp32)
    float4 aa0, aa1, ab0, ab1;        // A chunks fp32 path
    bf16x8 ba1, ba2;                  // A chunks bf16 path

    // preload tile 0
    wa0 = *(const float4*)(Wg1);  wa1 = *(const float4*)(Wg1 + 4);
    wb0 = *(const float4*)(Wg2);  wb1 = *(const float4*)(Wg2 + 4);
    if (final_mode) {
        ba1 = *(const bf16x8*)(Ag1b);
        ba2 = *(const bf16x8*)(Ag2b);
    } else {
        aa0 = *(const float4*)(Ag1f); aa1 = *(const float4*)(Ag1f + 4);
        ab0 = *(const float4*)(Ag2f); ab1 = *(const float4*)(Ag2f + 4);
    }

    int cur = 0;
    for (int kt = 0; kt < E_DIM; kt += 32) {
        // publish staged tile into buffer `cur` (convert here, after loads landed)
        if (final_mode) {
            *(bf16x8*)(As[cur] + r1 * 40 + o1) = ba1;
            *(bf16x8*)(As[cur] + r2 * 40 + o2) = ba2;
        } else {
            *(bf16x8*)(As[cur] + r1 * 40 + o1) = cvt8(aa0, aa1);
            *(bf16x8*)(As[cur] + r2 * 40 + o2) = cvt8(ab0, ab1);
        }
        *(bf16x8*)(Bs[cur] + r1 * 40 + o1) = cvt8(wa0, wa1);
        *(bf16x8*)(Bs[cur] + r2 * 40 + o2) = cvt8(wb0, wb1);
        __syncthreads();

        // issue loads for tile kt+32 (land during compute below)
        if (kt + 32 < E_DIM) {
            const int nk = kt + 32;
            wa0 = *(const float4*)(Wg1 + nk);  wa1 = *(const float4*)(Wg1 + nk + 4);
            wb0 = *(const float4*)(Wg2 + nk);  wb1 = *(const float4*)(Wg2 + nk + 4);
            if (final_mode) {
                ba1 = *(const bf16x8*)(Ag1b + nk);
                ba2 = *(const bf16x8*)(Ag2b + nk);
            } else {
                aa0 = *(const float4*)(Ag1f + nk); aa1 = *(const float4*)(Ag1f + nk + 4);
                ab0 = *(const float4*)(Ag2f + nk); ab1 = *(const float4*)(Ag2f + nk + 4);
            }
        }

        bf16x8 af[4], bfr[4];
#pragma unroll
        for (int i = 0; i < 4; i++)
            af[i] = *(const bf16x8*)(As[cur] + (wm + i * 16 + l16) * 40 + quad * 8);
#pragma unroll
        for (int j = 0; j < 4; j++)
            bfr[j] = *(const bf16x8*)(Bs[cur] + (wn + j * 16 + l16) * 40 + quad * 8);
#pragma unroll
        for (int i = 0; i < 4; i++)
#pragma unroll
            for (int j = 0; j < 4; j++)
                acc[i][j] = __builtin_amdgcn_mfma_f32_16x16x32_bf16(af[i], bfr[j], acc[i][j], 0, 0, 0);

        cur ^= 1;
    }

    // epilogue: C/D layout is col = lane&15, row = quad*4 + reg  [verified m89/m91]
#pragma unroll
    for (int j = 0; j < 4; j++) {
        const int n = bn + wn + j * 16 + l16;
        const float bv = bias[n];
#pragma unroll
        for (int i = 0; i < 4; i++) {
            const int m0 = bm + wm + i * 16 + quad * 4;
            if (mode == 3) {
#pragma unroll
                for (int r = 0; r < 4; r++)
                    outF[(size_t)(m0 + r) * E_DIM + n] = acc[i][j][r] + bv;
            } else if (mode == 2) {
                const int b_ = m0 >> 11, s0 = m0 & (S_LEN - 1);
                const int h = n >> 6, d = n & 63;
                bf16x4 pv;
#pragma unroll
                for (int r = 0; r < 4; r++) pv[r] = (bf16)(acc[i][j][r] + bv);
                *(bf16x4*)(outVt + ((size_t)((b_ * NH + h) * DH + d)) * S_LEN + s0) = pv;
            } else {
                bf16* o = (mode == 0) ? outQ : outK;
                const float sc = (mode == 0) ? 0.125f : 1.0f;
                const int h = n >> 6, d = n & 63;
#pragma unroll
                for (int r = 0; r < 4; r++) {
                    const int m = m0 + r;
                    const int b_ = m >> 11, s = m & (S_LEN - 1);
                    o[((size_t)(b_ * NH + h) * S_LEN + s) * DH + d] = (bf16)((acc[i][j][r] + bv) * sc);
                }
            }
        }
    }
}

// ---------------------------------------------------------------------------
// Flash attention, causal — R14 winner (512-thread blocks, balanced pairs,
// slim registers) with ONE change: Ps row stride 136 -> 140. Bank math:
// stride-136 P-writes put quads on banks {0,16,0,16} (4-way, 1.58x); 140
// gives {0,24,16,8} (2-way, free — m136). LDS 70 KB, still 2 blocks/CU.
// ---------------------------------------------------------------------------
__global__ __launch_bounds__(512, 2) void attn_kernel(
    const bf16* __restrict__ Qb, const bf16* __restrict__ Kb,
    const bf16* __restrict__ Vtb, bf16* __restrict__ Ob)
{
    __shared__ bf16 Ks[128 * 72];      // [kk][d]   18.0 KB
    __shared__ bf16 Vs[64 * 136];      // [d][kk]   17.0 KB
    __shared__ bf16 Ps[8][16 * 140];   // per-wave P stripe  35.0 KB

    const int t = threadIdx.x, lane = t & 63, w = t >> 6;   // w: 0..7
    const int quad = lane >> 4, l16 = lane & 15;

    const int i = blockIdx.x;
    const int xcd = i & 7, rr = i >> 3;        // rr: 0..31
    const int bh = (xcd << 2) | (rr & 3);
    const int pr = rr >> 2;                    // pair index 0..7
    const int qlo = pr, qhi = 15 - pr;         // the two 128-row q-tiles

    const bf16* Qg = Qb + (size_t)bh * S_LEN * DH;
    const bf16* Kg = Kb + (size_t)bh * S_LEN * DH;
    const bf16* Vg = Vtb + (size_t)bh * DH * S_LEN;
    const int b_ = bh >> 4, h = bh & 15;
    bf16* Og = Ob + (size_t)b_ * S_LEN * E_DIM + h * DH;

    bf16* Pw = Ps[w];
    const int inrow0 = w * 16;                 // wave's 16-row stripe in a q-tile

    bf16x8 aq[2][2];
#pragma unroll
    for (int qt = 0; qt < 2; qt++) {
        const int qrow0 = (qt ? qhi : qlo) * 128 + inrow0;
        const bf16* qp = Qg + (size_t)(qrow0 + l16) * DH + quad * 8;
        aq[qt][0] = *(const bf16x8*)(qp);
        aq[qt][1] = *(const bf16x8*)(qp + 32);
    }

    f32x4 o[2][4];
    float l_part[2][4];
#pragma unroll
    for (int qt = 0; qt < 2; qt++)
#pragma unroll
        for (int dt = 0; dt < 4; dt++) {
            o[qt][dt] = f32x4{0.f, 0.f, 0.f, 0.f};
            l_part[qt][dt] = 0.f;
        }

    const int T = qhi + 1;                     // staged k-tiles: 9..16
    const int kr0 = t >> 3, kce = (t & 7) * 8;     // K: rows kr0, kr0+64
    const int vr0 = t >> 4, vce = (t & 15) * 8;    // V: rows vr0, vr0+32

    for (int kt = 0; kt < T; kt++) {
        const int kb = kt * 128;
        uint4 k0 = *(const uint4*)(Kg + (size_t)(kb + kr0) * DH + kce);
        uint4 k1 = *(const uint4*)(Kg + (size_t)(kb + kr0 + 64) * DH + kce);
        uint4 v0 = *(const uint4*)(Vg + (size_t)vr0 * S_LEN + kb + vce);
        uint4 v1 = *(const uint4*)(Vg + (size_t)(vr0 + 32) * S_LEN + kb + vce);
        __syncthreads();
        *(uint4*)(Ks + kr0 * 72 + kce) = k0;
        *(uint4*)(Ks + (kr0 + 64) * 72 + kce) = k1;
        *(uint4*)(Vs + vr0 * 136 + vce) = v0;
        *(uint4*)(Vs + (vr0 + 32) * 136 + vce) = v1;
        __syncthreads();

#pragma unroll
        for (int qt = 0; qt < 2; qt++) {
            if (qt == 0 && kt > qlo) continue;
            const bool diag = qt ? (kt == qhi) : (kt == qlo);
            const int irb = inrow0 + quad * 4;

#pragma unroll
            for (int jt = 0; jt < 8; jt++) {
                const bf16* kp = Ks + (jt * 16 + l16) * 72 + quad * 8;
                bf16x8 bk0 = *(const bf16x8*)(kp);
                bf16x8 bk1 = *(const bf16x8*)(kp + 32);
                f32x4 s = f32x4{0.f, 0.f, 0.f, 0.f};
                s = __builtin_amdgcn_mfma_f32_16x16x32_bf16(aq[qt][0], bk0, s, 0, 0, 0);
                s = __builtin_amdgcn_mfma_f32_16x16x32_bf16(aq[qt][1], bk1, s, 0, 0, 0);
                const int kcol = jt * 16 + l16;
#pragma unroll
                for (int r = 0; r < 4; r++) {
                    float sval = s[r];
                    if (diag && kcol > irb + r) sval = NEG_INF;
                    const float pe = __expf(sval);
                    l_part[qt][r] += pe;
                    Pw[(quad * 4 + r) * 140 + jt * 16 + l16] = (bf16)pe;
                }
            }

#pragma unroll
            for (int ks = 0; ks < 4; ks++) {
                bf16x8 ap = *(const bf16x8*)(Pw + l16 * 140 + ks * 32 + quad * 8);
#pragma unroll
                for (int dt = 0; dt < 4; dt++) {
                    bf16x8 bv = *(const bf16x8*)(Vs + (dt * 16 + l16) * 136 + ks * 32 + quad * 8);
                    o[qt][dt] = __builtin_amdgcn_mfma_f32_16x16x32_bf16(ap, bv, o[qt][dt], 0, 0, 0);
                }
            }
        }
    }

#pragma unroll
    for (int qt = 0; qt < 2; qt++) {
        const int qrow0 = (qt ? qhi : qlo) * 128 + inrow0;
#pragma unroll
        for (int r = 0; r < 4; r++) {
            float l = l_part[qt][r];
            l += __shfl_xor(l, 1);
            l += __shfl_xor(l, 2);
            l += __shfl_xor(l, 4);
            l += __shfl_xor(l, 8);
            l_part[qt][r] = 1.0f / l;
        }
#pragma unroll
        for (int r = 0; r < 4; r++) {
            const int srow = qrow0 + quad * 4 + r;
#pragma unroll
            for (int dt = 0; dt < 4; dt++)
                Og[(size_t)srow * E_DIM + dt * 16 + l16] =
                    (bf16)(o[qt][dt][r] * l_part[qt][r]);
        }
    }
}

// ---------------------------------------------------------------------------
extern "C" void kernel_launch(void* const* d_in, const int* in_sizes, int n_in,
                              void* d_out, int out_size, void* d_ws, size_t ws_size,
                              hipStream_t stream)
{
    const float* x  = (const float*)d_in[0];
    const float* Wq = (const float*)d_in[1];
    const float* bq = (const float*)d_in[2];
    const float* Wk = (const float*)d_in[3];
    const float* bk = (const float*)d_in[4];
    const float* Wv = (const float*)d_in[5];
    const float* bv = (const float*)d_in[6];
    const float* Wo = (const float*)d_in[7];
    const float* bo = (const float*)d_in[8];
    float* out = (float*)d_out;

    char* ws = (char*)d_ws;
    const size_t MB = 1ull << 20;
    bf16* Qb  = (bf16*)(ws + 0);        //  8 MB: [b][h][s][d] (q pre-scaled by 1/8)
    bf16* Kb  = (bf16*)(ws + 8 * MB);   //  8 MB: [b][h][s][d]
    bf16* Vtb = (bf16*)(ws + 16 * MB);  //  8 MB: [b][h][d][s]
    bf16* Ab  = (bf16*)(ws + 24 * MB);  //  8 MB: attn out [b][s][e]

    // 1) Q/K/V projections with fused fp32->bf16 conversion
    gemm_kernel<<<dim3(8, 32, 3), 256, 0, stream>>>(
        x, nullptr, Wq, Wk, Wv, bq, bk, bv, Qb, Kb, Vtb, nullptr, 0);

    // 2) causal flash attention (R14 winner + Ps stride 140)
    attn_kernel<<<dim3(256), 512, 0, stream>>>(Qb, Kb, Vtb, Ab);

    // 3) output projection (bf16 A x fp32 Wo) -> fp32 d_out
    gemm_kernel<<<dim3(8, 32, 1), 256, 0, stream>>>(
        nullptr, Ab, Wo, Wo, Wo, bo, bo, bo, nullptr, nullptr, nullptr, out, 1);
}